// Round 4
// baseline (196.182 us; speedup 1.0000x reference)
//
#include <hip/hip_runtime.h>
#include <stdint.h>

#define NCOMP 8
#define LATD  512
#define HID   1024
#define OUTD  512
#define NS    16384

typedef unsigned short u16;
typedef __bf16 bf16x8 __attribute__((ext_vector_type(8)));
typedef float  f32x4  __attribute__((ext_vector_type(4)));

// ---- tile map: TM=128 for both gemms -> one shared map ----
#define MAPS       (NS/128 + NCOMP)        // 136 slots max
#define SLOT_CHUNK ((MAPS + 7)/8)          // 17 slots per XCD

// ---- workspace layout (bytes) ----
#define ORDER_OFF  2048
#define APACK_OFF  (ORDER_OFF + NS*4)
#define W1T_OFF    (APACK_OFF + (size_t)NS*LATD*2)
#define W2T_OFF    (W1T_OFF + (size_t)NCOMP*LATD*HID*2)
#define H_OFF      (W2T_OFF + (size_t)NCOMP*HID*OUTD*2)
#define WS_NEEDED  (H_OFF + (size_t)NS*HID*2)

// ---- dispatch geometry ----
#define PACK_B0   8
#define PACK_NB   2048                     // 8 samples per 256-thr block
#define W1T_B0    (PACK_B0 + PACK_NB)      // 2056
#define PREP_NB   (W1T_B0 + 1024)          // 3080
#define G1_JOBS   (8*SLOT_CHUNK*(HID/128)) // 1088

__device__ __forceinline__ u16 f2b(float f) {         // fp32 -> bf16 RNE
  unsigned int u = __builtin_bit_cast(unsigned int, f);
  u = (u + 0x7FFFu + ((u >> 16) & 1u)) >> 16;
  return (u16)u;
}

__device__ __forceinline__ void load_lds16(const void* g, void* l) {
  __builtin_amdgcn_global_load_lds((const __attribute__((address_space(1))) void*)g,
                                   (__attribute__((address_space(3))) void*)l, 16, 0, 0);
}

// ---- 64x64 transpose+convert tile job (256 threads), f32 src -> bf16 dst^T ----
// LDS reads hit each bank exactly 2x (free); stores are 8B, 128B-contiguous per 16 lanes.
__device__ __forceinline__
void wtrans64(const float* __restrict__ src, u16* __restrict__ dst,
              int CC, int R, int c0, int r0, float* tile /*[64*65]*/) {
  const int t = threadIdx.x;
  const int tx = t & 63, ty = t >> 6;      // 4 row-groups of 64
  for (int rr = ty; rr < 64; rr += 4)
    tile[rr*65 + tx] = src[(size_t)(r0+rr)*CC + c0 + tx];
  __syncthreads();
  const int ch = t & 15;
  #pragma unroll
  for (int q = 0; q < 4; ++q) {
    const int cc = (t >> 4) + (q << 4);
    float f0 = tile[((ch<<2)+0)*65 + cc];
    float f1 = tile[((ch<<2)+1)*65 + cc];
    float f2 = tile[((ch<<2)+2)*65 + cc];
    float f3 = tile[((ch<<2)+3)*65 + cc];
    uint2 pk;
    pk.x = (unsigned)f2b(f0) | ((unsigned)f2b(f1) << 16);
    pk.y = (unsigned)f2b(f2) | ((unsigned)f2b(f3) << 16);
    *reinterpret_cast<uint2*>(&dst[(size_t)(c0+cc)*R + r0 + (ch<<2)]) = pk;
  }
}

// ---------------- D1: prep (256-thr blocks, 8/CU resident) ----------------
// blocks 0..7       : bucketing (block c owns comp c)
// blocks 8..2055    : pack A (8 samples/block, original order)
// blocks 2056..3079 : W1 transpose+convert (W2 moved to D2)
__global__ __launch_bounds__(256)
void k_prep(const int* __restrict__ idx, const float* __restrict__ rho,
            const float* __restrict__ eps, const float* __restrict__ mu,
            const float* __restrict__ W1,
            int* __restrict__ offsets, int* __restrict__ ntiles,
            int* __restrict__ map, int* __restrict__ order,
            u16* __restrict__ Apack, u16* __restrict__ W1T) {
  __shared__ float tile[64*65];
  __shared__ int hist_s[NCOMP];
  __shared__ int wtot[4];
  const int b = blockIdx.x;
  const int t = threadIdx.x;

  if (b < NCOMP) {
    // ---- bucketing: 256 threads, 64 samples each; 16-bit packed per-thread hist ----
    const int c = b;
    const int wave = t >> 6, lane = t & 63;
    unsigned long long lo = 0, hi = 0;     // 4 comps x 16 bits each
    for (int i = 0; i < 64; ++i) {
      int v = idx[t + (i << 8)];
      unsigned long long one = 1ull << ((v & 3) << 4);
      if (v < 4) lo += one; else hi += one;
    }
    if (t < NCOMP) hist_s[t] = 0;
    __syncthreads();

    unsigned long long rlo = lo, rhi = hi; // wave sums <= 4096/field: no carry
    #pragma unroll
    for (int d = 1; d < 64; d <<= 1) { rlo += __shfl_xor(rlo, d); rhi += __shfl_xor(rhi, d); }
    if (lane == 0) {
      #pragma unroll
      for (int cc = 0; cc < 4; ++cc) atomicAdd(&hist_s[cc],   (int)((rlo >> (cc<<4)) & 0xffff));
      #pragma unroll
      for (int cc = 0; cc < 4; ++cc) atomicAdd(&hist_s[cc+4], (int)((rhi >> (cc<<4)) & 0xffff));
    }

    int v = (int)(((c < 4 ? lo : hi) >> ((c & 3) << 4)) & 0xffff);
    int s = v;
    #pragma unroll
    for (int d = 1; d < 64; d <<= 1) { int u = __shfl_up(s, d); if (lane >= d) s += u; }
    if (lane == 63) wtot[wave] = s;
    __syncthreads();

    int wbase = 0;
    for (int w = 0; w < wave; ++w) wbase += wtot[w];
    int off_c = 0;
    #pragma unroll
    for (int cc = 0; cc < NCOMP; ++cc) if (cc < c) off_c += hist_s[cc];

    int pos = off_c + wbase + (s - v);
    for (int i = 0; i < 64; ++i) {         // pass 2: re-read idx (L2-hot), scatter
      int smp = t + (i << 8);
      if (idx[smp] == c) order[pos++] = smp;
    }

    if (t == 0) {
      if (c == 0) {
        int a = 0;
        for (int cc = 0; cc < NCOMP; ++cc) { offsets[cc] = a; a += hist_s[cc]; }
        offsets[NCOMP] = a;
        int tot = 0;
        for (int cc = 0; cc < NCOMP; ++cc) tot += (hist_s[cc] + 127) >> 7;
        ntiles[0] = tot;
      }
      int mb = 0;
      for (int cc = 0; cc < c; ++cc) mb += (hist_s[cc] + 127) >> 7;
      int nt = (hist_s[c] + 127) >> 7;
      for (int m = 0; m < nt; ++m) map[mb + m] = (c << 16) | m;
    }
  } else if (b < W1T_B0) {
    // ---- pack: lat[i] = eps[i]*softplus(rho[idx[i]]) + mu[idx[i]], 8 samples/block ----
    const int base = (b - PACK_B0) << 3;
    #pragma unroll
    for (int it = 0; it < 2; ++it) {
      int i = base + (it << 2) + (t >> 6);  // 64 threads per sample
      int d = (t & 63) << 3;
      int c = idx[i];
      float r = rho[c];
      float sg = (r > 20.f) ? r : log1pf(expf(r));
      const float4* ep = reinterpret_cast<const float4*>(eps + (size_t)i*LATD + d);
      const float4* mp = reinterpret_cast<const float4*>(mu  + (size_t)c*LATD + d);
      float4 e0 = ep[0], e1 = ep[1], m0 = mp[0], m1 = mp[1];
      unsigned o0 = f2b(e0.x*sg+m0.x), o1 = f2b(e0.y*sg+m0.y), o2 = f2b(e0.z*sg+m0.z), o3 = f2b(e0.w*sg+m0.w);
      unsigned o4 = f2b(e1.x*sg+m1.x), o5 = f2b(e1.y*sg+m1.y), o6 = f2b(e1.z*sg+m1.z), o7 = f2b(e1.w*sg+m1.w);
      uint4 pk;
      pk.x = o0 | (o1<<16); pk.y = o2 | (o3<<16); pk.z = o4 | (o5<<16); pk.w = o6 | (o7<<16);
      *reinterpret_cast<uint4*>(Apack + (size_t)i*LATD + d) = pk;
    }
  } else {
    // ---- W1 [C][512][1024] -> W1T [C][1024][512] bf16, 128 tiles/comp ----
    int bb = b - W1T_B0;
    int comp = bb >> 7, loc = bb & 127;
    wtrans64(W1 + (size_t)comp*LATD*HID, W1T + (size_t)comp*LATD*HID,
             HID, LATD, (loc & 15) << 6, (loc >> 4) << 6, tile);
  }
}

// ---------------- tile-mapped bf16 GEMM body, 128x128, swizzled LDS ----------------
// A: [*][K] bf16.  BT: [C][NB][K] bf16 (B^T).  4 waves, 4x4 16x16x32 MFMA frags,
// BK=64, global_load_lds w=16, XOR-swizzled LDS staging.
// SWAPPED-OPERAND MFMA: acc[ni][mi] = mfma(bfr, af, acc) -> reg quad holds 4
// consecutive N-cols at one M-row; epilogue stores straight from registers.
template<int K, int NB, int STAGE>
__device__ __forceinline__
void gemm_tile(const int id, const u16* __restrict__ A, const u16* __restrict__ BT,
               const int* __restrict__ offsets, const int* __restrict__ ntiles,
               const int* __restrict__ map, const int* __restrict__ order,
               const float* __restrict__ bias,
               u16* __restrict__ Hout, float* __restrict__ Yout,
               u16* As, u16* Bs, int* ord) {
  constexpr int NCB = NB/128;
  const int xcd   = id & 7;
  const int sub   = id >> 3;
  const int ncolb = sub % NCB;
  const int slot  = xcd*SLOT_CHUNK + sub / NCB;
  if (slot >= ntiles[0]) return;
  const int packed = map[slot];
  const int c      = packed >> 16;
  const int bstart = offsets[c];
  const int bend   = offsets[c+1];
  const int tile0  = bstart + (packed & 0xffff)*128;
  const int ncol0  = ncolb*128;

  const int tid  = threadIdx.x;
  const int wave = tid >> 6;
  const int lane = tid & 63;
  const int srow = (wave<<5) + (lane>>3);                 // staging row (local)
  const int scol = ((lane & 7) ^ ((lane >> 3) & 7)) << 3; // swizzled source chunk

  if (STAGE == 2 && tid < 128) {
    int gr = tile0 + tid;
    ord[tid] = order[gr < bend ? gr : bstart];
  }

  size_t a_off[4], b_off[4];
  const size_t bbase = (size_t)c * NB * K;
  #pragma unroll
  for (int i = 0; i < 4; ++i) {
    int ar = tile0 + srow + (i<<3);
    if (ar >= bend) ar = bend - 1;            // clamp reads (stores guarded)
    int arow = (STAGE == 1) ? order[ar] : ar; // STAGE1: gather row via order
    a_off[i] = (size_t)arow * K + scol;
    b_off[i] = bbase + (size_t)(ncol0 + srow + (i<<3)) * K + scol;
  }

  const int wr   = (wave >> 1) << 6;
  const int wc   = (wave & 1) << 6;
  const int quad = lane >> 4;
  const int l16  = lane & 15;
  const int sw   = l16 & 7;                   // read-side swizzle key (= row&7)

  f32x4 acc[4][4] = {};                       // acc[ni][mi] (swapped layout)

  for (int k0 = 0; k0 < K; k0 += 64) {
    #pragma unroll
    for (int i = 0; i < 4; ++i)
      load_lds16(A + a_off[i] + k0, &As[((wave<<5) + (i<<3))<<6]);
    #pragma unroll
    for (int i = 0; i < 4; ++i)
      load_lds16(BT + b_off[i] + k0, &Bs[((wave<<5) + (i<<3))<<6]);
    __syncthreads();
    #pragma unroll
    for (int kk = 0; kk < 64; kk += 32) {
      const int kc = (kk >> 3) + quad;        // desired 16B chunk index
      const int sc = (kc ^ sw) << 3;          // swizzled LDS slot (elems)
      bf16x8 af[4], bfr[4];
      #pragma unroll
      for (int mi = 0; mi < 4; ++mi)
        af[mi] = *reinterpret_cast<const bf16x8*>(&As[((wr + (mi<<4) + l16)<<6) + sc]);
      #pragma unroll
      for (int ni = 0; ni < 4; ++ni)
        bfr[ni] = *reinterpret_cast<const bf16x8*>(&Bs[((wc + (ni<<4) + l16)<<6) + sc]);
      #pragma unroll
      for (int ni = 0; ni < 4; ++ni)
        #pragma unroll
        for (int mi = 0; mi < 4; ++mi)
          acc[ni][mi] = __builtin_amdgcn_mfma_f32_16x16x32_bf16(bfr[ni], af[mi], acc[ni][mi], 0, 0, 0);
    }
    __syncthreads();
  }

  // ---- epilogue (swapped C/D layout): M-row = wr+mi*16+l16 (per-lane),
  //      N-cols = wc+ni*16+quad*4+{0..3} (per reg quad, consecutive) ----
  f32x4 bias4[4];
  #pragma unroll
  for (int ni = 0; ni < 4; ++ni)
    bias4[ni] = *reinterpret_cast<const f32x4*>(
        &bias[(size_t)c*NB + ncol0 + wc + (ni<<4) + (quad<<2)]);

  #pragma unroll
  for (int mi = 0; mi < 4; ++mi) {
    const int row_l = wr + (mi<<4) + l16;
    const int grow  = tile0 + row_l;
    if (grow < bend) {
      #pragma unroll
      for (int ni = 0; ni < 4; ++ni) {
        const int col = ncol0 + wc + (ni<<4) + (quad<<2);
        float v0 = acc[ni][mi][0] + bias4[ni][0];
        float v1 = acc[ni][mi][1] + bias4[ni][1];
        float v2 = acc[ni][mi][2] + bias4[ni][2];
        float v3 = acc[ni][mi][3] + bias4[ni][3];
        if (STAGE == 1) {
          v0 = __builtin_amdgcn_rcpf(1.0f + __expf(-v0));
          v1 = __builtin_amdgcn_rcpf(1.0f + __expf(-v1));
          v2 = __builtin_amdgcn_rcpf(1.0f + __expf(-v2));
          v3 = __builtin_amdgcn_rcpf(1.0f + __expf(-v3));
          uint2 pk;
          pk.x = (unsigned)f2b(v0) | ((unsigned)f2b(v1) << 16);
          pk.y = (unsigned)f2b(v2) | ((unsigned)f2b(v3) << 16);
          *reinterpret_cast<uint2*>(&Hout[(size_t)grow*NB + col]) = pk;
        } else {
          float4 o; o.x = v0; o.y = v1; o.z = v2; o.w = v3;
          *reinterpret_cast<float4*>(&Yout[(size_t)ord[row_l]*NB + col]) = o;
        }
      }
    }
  }
}

// ---------------- D2: GEMM1 tiles + W2 transpose jobs in the tail ----------------
union __attribute__((aligned(16))) SmemU {
  struct { u16 As[128*64]; u16 Bs[128*64]; } g;
  float tile[64*65];
};

__global__ __launch_bounds__(256, 4)
void k_g1w2t(const u16* __restrict__ Apack, const u16* __restrict__ W1T,
             const float* __restrict__ W2,
             const int* __restrict__ offsets, const int* __restrict__ ntiles,
             const int* __restrict__ map, const int* __restrict__ order,
             const float* __restrict__ b1,
             u16* __restrict__ Hout, u16* __restrict__ W2T) {
  __shared__ SmemU sm;
  __shared__ int ord[128];
  const int id = blockIdx.x;
  if (id < G1_JOBS) {
    gemm_tile<LATD, HID, 1>(id, Apack, W1T, offsets, ntiles, map, order, b1,
                            Hout, nullptr, sm.g.As, sm.g.Bs, ord);
  } else {
    // W2 [C][1024][512] -> W2T [C][512][1024] bf16, 128 tiles/comp
    int bb = id - G1_JOBS;
    int comp = bb >> 7, loc = bb & 127;
    wtrans64(W2 + (size_t)comp*HID*OUTD, W2T + (size_t)comp*HID*OUTD,
             OUTD, HID, (loc & 7) << 6, (loc >> 3) << 6, sm.tile);
  }
}

// ---------------- D3: GEMM2 ----------------
__global__ __launch_bounds__(256, 4)
void k_gemm2(const u16* __restrict__ Hws, const u16* __restrict__ W2T,
             const int* __restrict__ offsets, const int* __restrict__ ntiles,
             const int* __restrict__ map, const int* __restrict__ order,
             const float* __restrict__ b2, float* __restrict__ Yout) {
  __shared__ __attribute__((aligned(16))) u16 As[128*64];
  __shared__ __attribute__((aligned(16))) u16 Bs[128*64];
  __shared__ int ord[128];
  gemm_tile<HID, OUTD, 2>(blockIdx.x, Hws, W2T, offsets, ntiles, map, order, b2,
                          nullptr, Yout, As, Bs, ord);
}

// ---------------- fallback (ws too small): naive per-sample MLP ----------------
__global__ void k_naive(const float* __restrict__ eps, const int* __restrict__ idx,
                        const float* __restrict__ mu, const float* __restrict__ rho,
                        const float* __restrict__ W1, const float* __restrict__ b1,
                        const float* __restrict__ W2, const float* __restrict__ b2,
                        float* __restrict__ out) {
  __shared__ float lat[LATD];
  __shared__ float h[HID];
  int n = blockIdx.x, t = threadIdx.x;
  int c = idx[n];
  float r = rho[c];
  float sg = (r > 20.f) ? r : log1pf(expf(r));
  for (int d = t; d < LATD; d += 256) lat[d] = eps[(size_t)n*LATD+d]*sg + mu[(size_t)c*LATD+d];
  __syncthreads();
  for (int j = t; j < HID; j += 256) {
    float a = b1[(size_t)c*HID+j];
    const float* w = W1 + (size_t)c*LATD*HID + j;
    for (int d = 0; d < LATD; ++d) a += lat[d]*w[(size_t)d*HID];
    h[j] = 1.f/(1.f+expf(-a));
  }
  __syncthreads();
  for (int o = t; o < OUTD; o += 256) {
    float a = b2[(size_t)c*OUTD+o];
    const float* w = W2 + (size_t)c*HID*OUTD + o;
    for (int j = 0; j < HID; ++j) a += h[j]*w[(size_t)j*OUTD];
    out[(size_t)n*OUTD+o] = a;
  }
}

extern "C" void kernel_launch(void* const* d_in, const int* in_sizes, int n_in,
                              void* d_out, int out_size, void* d_ws, size_t ws_size,
                              hipStream_t stream) {
  const float* eps = (const float*)d_in[0];
  const int*   idx = (const int*)d_in[1];
  const float* mu  = (const float*)d_in[2];
  const float* rho = (const float*)d_in[3];
  const float* W1  = (const float*)d_in[4];
  const float* b1  = (const float*)d_in[5];
  const float* W2  = (const float*)d_in[6];
  const float* b2  = (const float*)d_in[7];
  float* out = (float*)d_out;

  if (ws_size < WS_NEEDED) {     // insurance only
    k_naive<<<NS, 256, 0, stream>>>(eps, idx, mu, rho, W1, b1, W2, b2, out);
    return;
  }

  char* ws = (char*)d_ws;
  int*   offsets = (int*)(ws + 0);
  int*   ntiles  = (int*)(ws + 96);
  int*   map     = (int*)(ws + 128);
  int*   order   = (int*)(ws + ORDER_OFF);
  u16*   Apack   = (u16*)(ws + APACK_OFF);
  u16*   W1T     = (u16*)(ws + W1T_OFF);
  u16*   W2T     = (u16*)(ws + W2T_OFF);
  u16*   Hws     = (u16*)(ws + H_OFF);

  // D1: bucket (8) + pack (2048) + W1 transpose (1024), all 256-thr blocks
  k_prep<<<PREP_NB, 256, 0, stream>>>(
      idx, rho, eps, mu, W1, offsets, ntiles, map, order, Apack, W1T);
  // D2: GEMM1 (1088 tile jobs) + W2 transpose (1024 jobs fill the tail round)
  k_g1w2t<<<G1_JOBS + 1024, 256, 0, stream>>>(
      Apack, W1T, W2, offsets, ntiles, map, order, b1, Hws, W2T);
  // D3: GEMM2 [Nc x 1024] @ [1024 x 512] -> +b2 -> fp32 scatter out
  k_gemm2<<<8*SLOT_CHUNK*(OUTD/128), 256, 0, stream>>>(
      Hws, W2T, offsets, ntiles, map, order, b2, out);
}

// Round 5
// 190.192 us; speedup vs baseline: 1.0315x; 1.0315x over previous
//
#include <hip/hip_runtime.h>
#include <stdint.h>

#define NCOMP 8
#define LATD  512
#define HID   1024
#define OUTD  512
#define NS    16384

typedef unsigned short u16;
typedef __bf16 bf16x8 __attribute__((ext_vector_type(8)));
typedef float  f32x4  __attribute__((ext_vector_type(4)));

// ---- tile map: TM=128 for both gemms -> one shared map ----
#define MAPS       (NS/128 + NCOMP)        // 136 slots max
#define SLOT_CHUNK ((MAPS + 7)/8)          // 17 slots per XCD

// ---- workspace layout (bytes) ----
#define ORDER_OFF  2048
#define APACK_OFF  (ORDER_OFF + NS*4)
#define W1T_OFF    (APACK_OFF + (size_t)NS*LATD*2)
#define W2T_OFF    (W1T_OFF + (size_t)NCOMP*LATD*HID*2)
#define H_OFF      (W2T_OFF + (size_t)NCOMP*HID*OUTD*2)
#define WS_NEEDED  (H_OFF + (size_t)NS*HID*2)

// ---- prep dispatch geometry (all 256-thr blocks; 8 blocks/CU resident) ----
#define PACK_B0   8
#define PACK_NB   2048                     // 8 samples per block
#define W1T_B0    (PACK_B0 + PACK_NB)      // 2056
#define W2T_B0    (W1T_B0 + 1024)          // 3080
#define PREP_NB   (W2T_B0 + 1024)          // 4104  (= 2.004 residency rounds)

#define G1_JOBS   (8*SLOT_CHUNK*(HID/128)) // 1088
#define G2_JOBS   (8*SLOT_CHUNK*(OUTD/128))// 544

__device__ __forceinline__ u16 f2b(float f) {         // fp32 -> bf16 RNE
  unsigned int u = __builtin_bit_cast(unsigned int, f);
  u = (u + 0x7FFFu + ((u >> 16) & 1u)) >> 16;
  return (u16)u;
}

__device__ __forceinline__ void load_lds16(const void* g, void* l) {
  __builtin_amdgcn_global_load_lds((const __attribute__((address_space(1))) void*)g,
                                   (__attribute__((address_space(3))) void*)l, 16, 0, 0);
}

// ---- 64x64 transpose+convert tile job (256 threads), f32 src -> bf16 dst^T ----
// LDS reads hit each bank exactly 2x (free); stores are 8B, 128B-contiguous per 16 lanes.
__device__ __forceinline__
void wtrans64(const float* __restrict__ src, u16* __restrict__ dst,
              int CC, int R, int c0, int r0, float* tile /*[64*65]*/) {
  const int t = threadIdx.x;
  const int tx = t & 63, ty = t >> 6;      // 4 row-groups of 64
  for (int rr = ty; rr < 64; rr += 4)
    tile[rr*65 + tx] = src[(size_t)(r0+rr)*CC + c0 + tx];
  __syncthreads();
  const int ch = t & 15;
  #pragma unroll
  for (int q = 0; q < 4; ++q) {
    const int cc = (t >> 4) + (q << 4);
    float f0 = tile[((ch<<2)+0)*65 + cc];
    float f1 = tile[((ch<<2)+1)*65 + cc];
    float f2 = tile[((ch<<2)+2)*65 + cc];
    float f3 = tile[((ch<<2)+3)*65 + cc];
    uint2 pk;
    pk.x = (unsigned)f2b(f0) | ((unsigned)f2b(f1) << 16);
    pk.y = (unsigned)f2b(f2) | ((unsigned)f2b(f3) << 16);
    *reinterpret_cast<uint2*>(&dst[(size_t)(c0+cc)*R + r0 + (ch<<2)]) = pk;
  }
}

// ---------------- D1: prep (256-thr blocks) ----------------
// blocks 0..7       : bucketing (block c owns comp c)
// blocks 8..2055    : pack A (8 samples/block, original order)
// blocks 2056..3079 : W1 transpose+convert
// blocks 3080..4103 : W2 transpose+convert
__global__ __launch_bounds__(256)
void k_prep(const int* __restrict__ idx, const float* __restrict__ rho,
            const float* __restrict__ eps, const float* __restrict__ mu,
            const float* __restrict__ W1, const float* __restrict__ W2,
            int* __restrict__ offsets, int* __restrict__ ntiles,
            int* __restrict__ map, int* __restrict__ order,
            u16* __restrict__ Apack, u16* __restrict__ W1T, u16* __restrict__ W2T) {
  __shared__ float tile[64*65];
  __shared__ int hist_s[NCOMP];
  __shared__ int wtot[4];
  const int b = blockIdx.x;
  const int t = threadIdx.x;

  if (b < NCOMP) {
    // ---- bucketing: 256 threads, 64 samples each; 16-bit packed per-thread hist ----
    const int c = b;
    const int wave = t >> 6, lane = t & 63;
    unsigned long long lo = 0, hi = 0;     // 4 comps x 16 bits each
    for (int i = 0; i < 64; ++i) {
      int v = idx[t + (i << 8)];
      unsigned long long one = 1ull << ((v & 3) << 4);
      if (v < 4) lo += one; else hi += one;
    }
    if (t < NCOMP) hist_s[t] = 0;
    __syncthreads();

    unsigned long long rlo = lo, rhi = hi; // wave sums <= 4096/field: no carry
    #pragma unroll
    for (int d = 1; d < 64; d <<= 1) { rlo += __shfl_xor(rlo, d); rhi += __shfl_xor(rhi, d); }
    if (lane == 0) {
      #pragma unroll
      for (int cc = 0; cc < 4; ++cc) atomicAdd(&hist_s[cc],   (int)((rlo >> (cc<<4)) & 0xffff));
      #pragma unroll
      for (int cc = 0; cc < 4; ++cc) atomicAdd(&hist_s[cc+4], (int)((rhi >> (cc<<4)) & 0xffff));
    }

    int v = (int)(((c < 4 ? lo : hi) >> ((c & 3) << 4)) & 0xffff);
    int s = v;
    #pragma unroll
    for (int d = 1; d < 64; d <<= 1) { int u = __shfl_up(s, d); if (lane >= d) s += u; }
    if (lane == 63) wtot[wave] = s;
    __syncthreads();

    int wbase = 0;
    for (int w = 0; w < wave; ++w) wbase += wtot[w];
    int off_c = 0;
    #pragma unroll
    for (int cc = 0; cc < NCOMP; ++cc) if (cc < c) off_c += hist_s[cc];

    int pos = off_c + wbase + (s - v);
    for (int i = 0; i < 64; ++i) {         // pass 2: re-read idx (L2-hot), scatter
      int smp = t + (i << 8);
      if (idx[smp] == c) order[pos++] = smp;
    }

    if (t == 0) {
      if (c == 0) {
        int a = 0;
        for (int cc = 0; cc < NCOMP; ++cc) { offsets[cc] = a; a += hist_s[cc]; }
        offsets[NCOMP] = a;
        int tot = 0;
        for (int cc = 0; cc < NCOMP; ++cc) tot += (hist_s[cc] + 127) >> 7;
        ntiles[0] = tot;
      }
      int mb = 0;
      for (int cc = 0; cc < c; ++cc) mb += (hist_s[cc] + 127) >> 7;
      int nt = (hist_s[c] + 127) >> 7;
      for (int m = 0; m < nt; ++m) map[mb + m] = (c << 16) | m;
    }
  } else if (b < W1T_B0) {
    // ---- pack: lat[i] = eps[i]*softplus(rho[idx[i]]) + mu[idx[i]], 8 samples/block ----
    const int base = (b - PACK_B0) << 3;
    #pragma unroll
    for (int it = 0; it < 2; ++it) {
      int i = base + (it << 2) + (t >> 6);  // 64 threads per sample
      int d = (t & 63) << 3;
      int c = idx[i];
      float r = rho[c];
      float sg = (r > 20.f) ? r : log1pf(expf(r));
      const float4* ep = reinterpret_cast<const float4*>(eps + (size_t)i*LATD + d);
      const float4* mp = reinterpret_cast<const float4*>(mu  + (size_t)c*LATD + d);
      float4 e0 = ep[0], e1 = ep[1], m0 = mp[0], m1 = mp[1];
      unsigned o0 = f2b(e0.x*sg+m0.x), o1 = f2b(e0.y*sg+m0.y), o2 = f2b(e0.z*sg+m0.z), o3 = f2b(e0.w*sg+m0.w);
      unsigned o4 = f2b(e1.x*sg+m1.x), o5 = f2b(e1.y*sg+m1.y), o6 = f2b(e1.z*sg+m1.z), o7 = f2b(e1.w*sg+m1.w);
      uint4 pk;
      pk.x = o0 | (o1<<16); pk.y = o2 | (o3<<16); pk.z = o4 | (o5<<16); pk.w = o6 | (o7<<16);
      *reinterpret_cast<uint4*>(Apack + (size_t)i*LATD + d) = pk;
    }
  } else if (b < W2T_B0) {
    // ---- W1 [C][512][1024] -> W1T [C][1024][512] bf16, 128 tiles/comp ----
    int bb = b - W1T_B0;
    int comp = bb >> 7, loc = bb & 127;
    wtrans64(W1 + (size_t)comp*LATD*HID, W1T + (size_t)comp*LATD*HID,
             HID, LATD, (loc & 15) << 6, (loc >> 4) << 6, tile);
  } else {
    // ---- W2 [C][1024][512] -> W2T [C][512][1024] bf16, 128 tiles/comp ----
    int bb = b - W2T_B0;
    int comp = bb >> 7, loc = bb & 127;
    wtrans64(W2 + (size_t)comp*HID*OUTD, W2T + (size_t)comp*HID*OUTD,
             OUTD, HID, (loc & 7) << 6, (loc >> 3) << 6, tile);
  }
}

// ---------------- tile-mapped bf16 GEMM body, 128x128, swizzled LDS ----------------
// A: [*][K] bf16.  BT: [C][NB][K] bf16 (B^T).  4 waves, 4x4 16x16x32 MFMA frags,
// BK=64, global_load_lds w=16, XOR-swizzled LDS staging.
// SWAPPED-OPERAND MFMA: acc[ni][mi] = mfma(bfr, af, acc) -> reg quad holds 4
// consecutive N-cols at one M-row; epilogue stores straight from registers.
template<int K, int NB, int STAGE>
__device__ __forceinline__
void gemm_tile(const int id, const u16* __restrict__ A, const u16* __restrict__ BT,
               const int* __restrict__ offsets, const int* __restrict__ ntiles,
               const int* __restrict__ map, const int* __restrict__ order,
               const float* __restrict__ bias,
               u16* __restrict__ Hout, float* __restrict__ Yout,
               u16* As, u16* Bs, int* ord) {
  constexpr int NCB = NB/128;
  const int xcd   = id & 7;
  const int sub   = id >> 3;
  const int ncolb = sub % NCB;
  const int slot  = xcd*SLOT_CHUNK + sub / NCB;
  if (slot >= ntiles[0]) return;             // uniform per block
  const int packed = map[slot];
  const int c      = packed >> 16;
  const int bstart = offsets[c];
  const int bend   = offsets[c+1];
  const int tile0  = bstart + (packed & 0xffff)*128;
  const int ncol0  = ncolb*128;

  const int tid  = threadIdx.x;
  const int wave = tid >> 6;
  const int lane = tid & 63;
  const int srow = (wave<<5) + (lane>>3);                 // staging row (local)
  const int scol = ((lane & 7) ^ ((lane >> 3) & 7)) << 3; // swizzled source chunk

  if (STAGE == 2 && tid < 128) {
    int gr = tile0 + tid;
    ord[tid] = order[gr < bend ? gr : bstart];
  }

  size_t a_off[4], b_off[4];
  const size_t bbase = (size_t)c * NB * K;
  #pragma unroll
  for (int i = 0; i < 4; ++i) {
    int ar = tile0 + srow + (i<<3);
    if (ar >= bend) ar = bend - 1;            // clamp reads (stores guarded)
    int arow = (STAGE == 1) ? order[ar] : ar; // STAGE1: gather row via order
    a_off[i] = (size_t)arow * K + scol;
    b_off[i] = bbase + (size_t)(ncol0 + srow + (i<<3)) * K + scol;
  }

  const int wr   = (wave >> 1) << 6;
  const int wc   = (wave & 1) << 6;
  const int quad = lane >> 4;
  const int l16  = lane & 15;
  const int sw   = l16 & 7;                   // read-side swizzle key (= row&7)

  f32x4 acc[4][4] = {};                       // acc[ni][mi] (swapped layout)

  for (int k0 = 0; k0 < K; k0 += 64) {
    #pragma unroll
    for (int i = 0; i < 4; ++i)
      load_lds16(A + a_off[i] + k0, &As[((wave<<5) + (i<<3))<<6]);
    #pragma unroll
    for (int i = 0; i < 4; ++i)
      load_lds16(BT + b_off[i] + k0, &Bs[((wave<<5) + (i<<3))<<6]);
    __syncthreads();
    #pragma unroll
    for (int kk = 0; kk < 64; kk += 32) {
      const int kc = (kk >> 3) + quad;        // desired 16B chunk index
      const int sc = (kc ^ sw) << 3;          // swizzled LDS slot (elems)
      bf16x8 af[4], bfr[4];
      #pragma unroll
      for (int mi = 0; mi < 4; ++mi)
        af[mi] = *reinterpret_cast<const bf16x8*>(&As[((wr + (mi<<4) + l16)<<6) + sc]);
      #pragma unroll
      for (int ni = 0; ni < 4; ++ni)
        bfr[ni] = *reinterpret_cast<const bf16x8*>(&Bs[((wc + (ni<<4) + l16)<<6) + sc]);
      #pragma unroll
      for (int ni = 0; ni < 4; ++ni)
        #pragma unroll
        for (int mi = 0; mi < 4; ++mi)
          acc[ni][mi] = __builtin_amdgcn_mfma_f32_16x16x32_bf16(bfr[ni], af[mi], acc[ni][mi], 0, 0, 0);
    }
    __syncthreads();
  }

  // ---- epilogue (swapped C/D layout): M-row = wr+mi*16+l16 (per-lane),
  //      N-cols = wc+ni*16+quad*4+{0..3} (per reg quad, consecutive) ----
  f32x4 bias4[4];
  #pragma unroll
  for (int ni = 0; ni < 4; ++ni)
    bias4[ni] = *reinterpret_cast<const f32x4*>(
        &bias[(size_t)c*NB + ncol0 + wc + (ni<<4) + (quad<<2)]);

  #pragma unroll
  for (int mi = 0; mi < 4; ++mi) {
    const int row_l = wr + (mi<<4) + l16;
    const int grow  = tile0 + row_l;
    if (grow < bend) {
      #pragma unroll
      for (int ni = 0; ni < 4; ++ni) {
        const int col = ncol0 + wc + (ni<<4) + (quad<<2);
        float v0 = acc[ni][mi][0] + bias4[ni][0];
        float v1 = acc[ni][mi][1] + bias4[ni][1];
        float v2 = acc[ni][mi][2] + bias4[ni][2];
        float v3 = acc[ni][mi][3] + bias4[ni][3];
        if (STAGE == 1) {
          v0 = __builtin_amdgcn_rcpf(1.0f + __expf(-v0));
          v1 = __builtin_amdgcn_rcpf(1.0f + __expf(-v1));
          v2 = __builtin_amdgcn_rcpf(1.0f + __expf(-v2));
          v3 = __builtin_amdgcn_rcpf(1.0f + __expf(-v3));
          uint2 pk;
          pk.x = (unsigned)f2b(v0) | ((unsigned)f2b(v1) << 16);
          pk.y = (unsigned)f2b(v2) | ((unsigned)f2b(v3) << 16);
          *reinterpret_cast<uint2*>(&Hout[(size_t)grow*NB + col]) = pk;
        } else {
          float4 o; o.x = v0; o.y = v1; o.z = v2; o.w = v3;
          *reinterpret_cast<float4*>(&Yout[(size_t)ord[row_l]*NB + col]) = o;
        }
      }
    }
  }
}

// ---------------- D2: GEMM1, persistent 1024 blocks (exactly 4/CU, no straggler round) ----
// blocks 0..63 handle jobs {b, b+1024} (same XCD: 1024 % 8 == 0); 64..1023 one job.
__global__ __launch_bounds__(256, 4)
void k_gemm1(const u16* __restrict__ Apack, const u16* __restrict__ W1T,
             const int* __restrict__ offsets, const int* __restrict__ ntiles,
             const int* __restrict__ map, const int* __restrict__ order,
             const float* __restrict__ b1, u16* __restrict__ Hout) {
  __shared__ __attribute__((aligned(16))) u16 As[128*64];
  __shared__ __attribute__((aligned(16))) u16 Bs[128*64];
  __shared__ int ord[128];
  #pragma unroll
  for (int j = 0; j < 2; ++j) {
    const int id = blockIdx.x + (j << 10);
    if (id < G1_JOBS) {
      if (j) __syncthreads();                // protect LDS reuse across jobs
      gemm_tile<LATD, HID, 1>(id, Apack, W1T, offsets, ntiles, map, order, b1,
                              Hout, nullptr, As, Bs, ord);
    }
  }
}

// ---------------- D3: GEMM2 (544 jobs < 1024 slots: direct) ----------------
__global__ __launch_bounds__(256, 4)
void k_gemm2(const u16* __restrict__ Hws, const u16* __restrict__ W2T,
             const int* __restrict__ offsets, const int* __restrict__ ntiles,
             const int* __restrict__ map, const int* __restrict__ order,
             const float* __restrict__ b2, float* __restrict__ Yout) {
  __shared__ __attribute__((aligned(16))) u16 As[128*64];
  __shared__ __attribute__((aligned(16))) u16 Bs[128*64];
  __shared__ int ord[128];
  gemm_tile<HID, OUTD, 2>(blockIdx.x, Hws, W2T, offsets, ntiles, map, order, b2,
                          nullptr, Yout, As, Bs, ord);
}

// ---------------- fallback (ws too small): naive per-sample MLP ----------------
__global__ void k_naive(const float* __restrict__ eps, const int* __restrict__ idx,
                        const float* __restrict__ mu, const float* __restrict__ rho,
                        const float* __restrict__ W1, const float* __restrict__ b1,
                        const float* __restrict__ W2, const float* __restrict__ b2,
                        float* __restrict__ out) {
  __shared__ float lat[LATD];
  __shared__ float h[HID];
  int n = blockIdx.x, t = threadIdx.x;
  int c = idx[n];
  float r = rho[c];
  float sg = (r > 20.f) ? r : log1pf(expf(r));
  for (int d = t; d < LATD; d += 256) lat[d] = eps[(size_t)n*LATD+d]*sg + mu[(size_t)c*LATD+d];
  __syncthreads();
  for (int j = t; j < HID; j += 256) {
    float a = b1[(size_t)c*HID+j];
    const float* w = W1 + (size_t)c*LATD*HID + j;
    for (int d = 0; d < LATD; ++d) a += lat[d]*w[(size_t)d*HID];
    h[j] = 1.f/(1.f+expf(-a));
  }
  __syncthreads();
  for (int o = t; o < OUTD; o += 256) {
    float a = b2[(size_t)c*OUTD+o];
    const float* w = W2 + (size_t)c*HID*OUTD + o;
    for (int j = 0; j < HID; ++j) a += h[j]*w[(size_t)j*OUTD];
    out[(size_t)n*OUTD+o] = a;
  }
}

extern "C" void kernel_launch(void* const* d_in, const int* in_sizes, int n_in,
                              void* d_out, int out_size, void* d_ws, size_t ws_size,
                              hipStream_t stream) {
  const float* eps = (const float*)d_in[0];
  const int*   idx = (const int*)d_in[1];
  const float* mu  = (const float*)d_in[2];
  const float* rho = (const float*)d_in[3];
  const float* W1  = (const float*)d_in[4];
  const float* b1  = (const float*)d_in[5];
  const float* W2  = (const float*)d_in[6];
  const float* b2  = (const float*)d_in[7];
  float* out = (float*)d_out;

  if (ws_size < WS_NEEDED) {     // insurance only
    k_naive<<<NS, 256, 0, stream>>>(eps, idx, mu, rho, W1, b1, W2, b2, out);
    return;
  }

  char* ws = (char*)d_ws;
  int*   offsets = (int*)(ws + 0);
  int*   ntiles  = (int*)(ws + 96);
  int*   map     = (int*)(ws + 128);
  int*   order   = (int*)(ws + ORDER_OFF);
  u16*   Apack   = (u16*)(ws + APACK_OFF);
  u16*   W1T     = (u16*)(ws + W1T_OFF);
  u16*   W2T     = (u16*)(ws + W2T_OFF);
  u16*   Hws     = (u16*)(ws + H_OFF);

  // D1: bucket (8) + pack (2048) + W1T (1024) + W2T (1024), all 256-thr blocks
  k_prep<<<PREP_NB, 256, 0, stream>>>(
      idx, rho, eps, mu, W1, W2, offsets, ntiles, map, order, Apack, W1T, W2T);
  // D2: GEMM1 gather-A [Nc x 512] @ [512 x 1024] -> sigmoid -> H (bf16, bucket order)
  k_gemm1<<<1024, 256, 0, stream>>>(
      Apack, W1T, offsets, ntiles, map, order, b1, Hws);
  // D3: GEMM2 [Nc x 1024] @ [1024 x 512] -> +b2 -> fp32 scatter out
  k_gemm2<<<G2_JOBS, 256, 0, stream>>>(
      Hws, W2T, offsets, ntiles, map, order, b2, out);
}

// Round 6
// 188.627 us; speedup vs baseline: 1.0401x; 1.0083x over previous
//
#include <hip/hip_runtime.h>
#include <stdint.h>

#define NCOMP 8
#define LATD  512
#define HID   1024
#define OUTD  512
#define NS    16384

typedef unsigned short u16;
typedef __bf16 bf16x8 __attribute__((ext_vector_type(8)));
typedef float  f32x4  __attribute__((ext_vector_type(4)));

// ---- tile map: TM=128 for both gemms -> one shared map ----
#define MAPS       (NS/128 + NCOMP)        // 136 slots max
#define SLOT_CHUNK ((MAPS + 7)/8)          // 17 slots per XCD

// ---- workspace layout (bytes) ----
#define ORDER_OFF  2048
#define APACK_OFF  (ORDER_OFF + NS*4)
#define W1T_OFF    (APACK_OFF + (size_t)NS*LATD*2)
#define W2T_OFF    (W1T_OFF + (size_t)NCOMP*LATD*HID*2)
#define H_OFF      (W2T_OFF + (size_t)NCOMP*HID*OUTD*2)
#define WS_NEEDED  (H_OFF + (size_t)NS*HID*2)

// ---- prep dispatch geometry (all 256-thr blocks) ----
#define PACK_B0   8
#define PACK_NB   1024                     // 16 samples per block (2/wave/iter x 2 iter)
#define W1T_B0    (PACK_B0 + PACK_NB)      // 1032
#define W2T_B0    (W1T_B0 + 1024)          // 2056
#define PREP_NB   (W2T_B0 + 1024)          // 3080

#define G1_JOBS   (8*SLOT_CHUNK*(HID/128)) // 1088
#define G2_JOBS   (8*SLOT_CHUNK*(OUTD/128))// 544

__device__ __forceinline__ u16 f2b(float f) {         // fp32 -> bf16 RNE
  unsigned int u = __builtin_bit_cast(unsigned int, f);
  u = (u + 0x7FFFu + ((u >> 16) & 1u)) >> 16;
  return (u16)u;
}

__device__ __forceinline__ unsigned pk2(float a, float b) {
  return (unsigned)f2b(a) | ((unsigned)f2b(b) << 16);
}

__device__ __forceinline__ void load_lds16(const void* g, void* l) {
  __builtin_amdgcn_global_load_lds((const __attribute__((address_space(1))) void*)g,
                                   (__attribute__((address_space(3))) void*)l, 16, 0, 0);
}

// ---- 64x64 transpose+convert tile job (256 threads), f32 src -> bf16 dst^T ----
// Wide version: 4x float4 global loads/thread (64B in flight), 2x uint4 stores.
// LDS bank math (65-pad): writes 2 lanes/bank, reads 2 lanes/bank -> free.
__device__ __forceinline__
void wtrans64(const float* __restrict__ src, u16* __restrict__ dst,
              int CC, int R, int c0, int r0, float* tile /*[64*65]*/) {
  const int t = threadIdx.x;
  const int tx4 = (t & 15) << 2;           // col chunk 0,4,...,60
  const int ty  = t >> 4;                  // row 0..15
  float4 v[4];
  #pragma unroll
  for (int r = 0; r < 4; ++r)
    v[r] = *reinterpret_cast<const float4*>(&src[(size_t)(r0 + ty + (r<<4))*CC + c0 + tx4]);
  #pragma unroll
  for (int r = 0; r < 4; ++r) {
    const int rr = ty + (r<<4);
    tile[rr*65 + tx4 + 0] = v[r].x;
    tile[rr*65 + tx4 + 1] = v[r].y;
    tile[rr*65 + tx4 + 2] = v[r].z;
    tile[rr*65 + tx4 + 3] = v[r].w;
  }
  __syncthreads();
  const int ch = t & 7;                    // 8-row chunk -> 16B store
  const int cc = t >> 3;                   // 0..31
  #pragma unroll
  for (int q = 0; q < 2; ++q) {
    const int col = cc + (q << 5);
    uint4 o;
    o.x = pk2(tile[((ch<<3)+0)*65 + col], tile[((ch<<3)+1)*65 + col]);
    o.y = pk2(tile[((ch<<3)+2)*65 + col], tile[((ch<<3)+3)*65 + col]);
    o.z = pk2(tile[((ch<<3)+4)*65 + col], tile[((ch<<3)+5)*65 + col]);
    o.w = pk2(tile[((ch<<3)+6)*65 + col], tile[((ch<<3)+7)*65 + col]);
    *reinterpret_cast<uint4*>(&dst[(size_t)(c0+col)*R + r0 + (ch<<3)]) = o;
  }
}

// ---------------- D1: prep (256-thr blocks) ----------------
// blocks 0..7       : bucketing (block c owns comp c)
// blocks 8..1031    : pack A (16 samples/block, 2 interleaved chains/wave)
// blocks 1032..2055 : W1 transpose+convert
// blocks 2056..3079 : W2 transpose+convert
__global__ __launch_bounds__(256)
void k_prep(const int* __restrict__ idx, const float* __restrict__ rho,
            const float* __restrict__ eps, const float* __restrict__ mu,
            const float* __restrict__ W1, const float* __restrict__ W2,
            int* __restrict__ offsets, int* __restrict__ ntiles,
            int* __restrict__ map, int* __restrict__ order,
            u16* __restrict__ Apack, u16* __restrict__ W1T, u16* __restrict__ W2T) {
  __shared__ float tile[64*65];
  __shared__ int hist_s[NCOMP];
  __shared__ int wtot[4];
  const int b = blockIdx.x;
  const int t = threadIdx.x;

  if (b < NCOMP) {
    // ---- bucketing: 256 threads, 64 samples each; 16-bit packed per-thread hist ----
    const int c = b;
    const int wave = t >> 6, lane = t & 63;
    unsigned long long lo = 0, hi = 0;     // 4 comps x 16 bits each
    for (int i = 0; i < 64; ++i) {
      int v = idx[t + (i << 8)];
      unsigned long long one = 1ull << ((v & 3) << 4);
      if (v < 4) lo += one; else hi += one;
    }
    if (t < NCOMP) hist_s[t] = 0;
    __syncthreads();

    unsigned long long rlo = lo, rhi = hi; // wave sums <= 4096/field: no carry
    #pragma unroll
    for (int d = 1; d < 64; d <<= 1) { rlo += __shfl_xor(rlo, d); rhi += __shfl_xor(rhi, d); }
    if (lane == 0) {
      #pragma unroll
      for (int cc = 0; cc < 4; ++cc) atomicAdd(&hist_s[cc],   (int)((rlo >> (cc<<4)) & 0xffff));
      #pragma unroll
      for (int cc = 0; cc < 4; ++cc) atomicAdd(&hist_s[cc+4], (int)((rhi >> (cc<<4)) & 0xffff));
    }

    int v = (int)(((c < 4 ? lo : hi) >> ((c & 3) << 4)) & 0xffff);
    int s = v;
    #pragma unroll
    for (int d = 1; d < 64; d <<= 1) { int u = __shfl_up(s, d); if (lane >= d) s += u; }
    if (lane == 63) wtot[wave] = s;
    __syncthreads();

    int wbase = 0;
    for (int w = 0; w < wave; ++w) wbase += wtot[w];
    int off_c = 0;
    #pragma unroll
    for (int cc = 0; cc < NCOMP; ++cc) if (cc < c) off_c += hist_s[cc];

    int pos = off_c + wbase + (s - v);
    for (int i = 0; i < 64; ++i) {         // pass 2: re-read idx (L2-hot), scatter
      int smp = t + (i << 8);
      if (idx[smp] == c) order[pos++] = smp;
    }

    if (t == 0) {
      if (c == 0) {
        int a = 0;
        for (int cc = 0; cc < NCOMP; ++cc) { offsets[cc] = a; a += hist_s[cc]; }
        offsets[NCOMP] = a;
        int tot = 0;
        for (int cc = 0; cc < NCOMP; ++cc) tot += (hist_s[cc] + 127) >> 7;
        ntiles[0] = tot;
      }
      int mb = 0;
      for (int cc = 0; cc < c; ++cc) mb += (hist_s[cc] + 127) >> 7;
      int nt = (hist_s[c] + 127) >> 7;
      for (int m = 0; m < nt; ++m) map[mb + m] = (c << 16) | m;
    }
  } else if (b < W1T_B0) {
    // ---- pack: lat = eps*softplus(rho[c]) + mu[c]; 2 interleaved samples/wave ----
    const int wave = t >> 6, lane = t & 63;
    const int base = ((b - PACK_B0) << 4) + (wave << 1);
    const float4* eps4 = reinterpret_cast<const float4*>(eps);
    const float4* mu4  = reinterpret_cast<const float4*>(mu);
    uint2* ap2 = reinterpret_cast<uint2*>(Apack);
    #pragma unroll
    for (int it = 0; it < 2; ++it) {
      const int s0 = base + (it << 3);
      const int s1 = s0 + 1;
      int ca = idx[s0], cb = idx[s1];
      float ra = rho[ca], rb = rho[cb];
      float sga = (ra > 20.f) ? ra : log1pf(expf(ra));
      float sgb = (rb > 20.f) ? rb : log1pf(expf(rb));
      // 8 full-density float4 loads in flight (2 samples x {eps,mu} x 2 halves)
      float4 ea0 = eps4[(size_t)s0*128 + lane];
      float4 ea1 = eps4[(size_t)s0*128 + 64 + lane];
      float4 eb0 = eps4[(size_t)s1*128 + lane];
      float4 eb1 = eps4[(size_t)s1*128 + 64 + lane];
      float4 ma0 = mu4[(size_t)ca*128 + lane];
      float4 ma1 = mu4[(size_t)ca*128 + 64 + lane];
      float4 mb0 = mu4[(size_t)cb*128 + lane];
      float4 mb1 = mu4[(size_t)cb*128 + 64 + lane];
      uint2 oa0, oa1, ob0, ob1;
      oa0.x = pk2(ea0.x*sga+ma0.x, ea0.y*sga+ma0.y);
      oa0.y = pk2(ea0.z*sga+ma0.z, ea0.w*sga+ma0.w);
      oa1.x = pk2(ea1.x*sga+ma1.x, ea1.y*sga+ma1.y);
      oa1.y = pk2(ea1.z*sga+ma1.z, ea1.w*sga+ma1.w);
      ob0.x = pk2(eb0.x*sgb+mb0.x, eb0.y*sgb+mb0.y);
      ob0.y = pk2(eb0.z*sgb+mb0.z, eb0.w*sgb+mb0.w);
      ob1.x = pk2(eb1.x*sgb+mb1.x, eb1.y*sgb+mb1.y);
      ob1.y = pk2(eb1.z*sgb+mb1.z, eb1.w*sgb+mb1.w);
      ap2[(size_t)s0*128 + lane]      = oa0;
      ap2[(size_t)s0*128 + 64 + lane] = oa1;
      ap2[(size_t)s1*128 + lane]      = ob0;
      ap2[(size_t)s1*128 + 64 + lane] = ob1;
    }
  } else if (b < W2T_B0) {
    // ---- W1 [C][512][1024] -> W1T [C][1024][512] bf16, 128 tiles/comp ----
    int bb = b - W1T_B0;
    int comp = bb >> 7, loc = bb & 127;
    wtrans64(W1 + (size_t)comp*LATD*HID, W1T + (size_t)comp*LATD*HID,
             HID, LATD, (loc & 15) << 6, (loc >> 4) << 6, tile);
  } else {
    // ---- W2 [C][1024][512] -> W2T [C][512][1024] bf16, 128 tiles/comp ----
    int bb = b - W2T_B0;
    int comp = bb >> 7, loc = bb & 127;
    wtrans64(W2 + (size_t)comp*HID*OUTD, W2T + (size_t)comp*HID*OUTD,
             OUTD, HID, (loc & 7) << 6, (loc >> 3) << 6, tile);
  }
}

// ---------------- tile-mapped bf16 GEMM body, 128x128, swizzled LDS ----------------
// A: [*][K] bf16.  BT: [C][NB][K] bf16 (B^T).  4 waves, 4x4 16x16x32 MFMA frags,
// BK=64, global_load_lds w=16, XOR-swizzled LDS staging.
// SWAPPED-OPERAND MFMA: acc[ni][mi] = mfma(bfr, af, acc) -> reg quad holds 4
// consecutive N-cols at one M-row; epilogue stores straight from registers.
template<int K, int NB, int STAGE>
__device__ __forceinline__
void gemm_tile(const int id, const u16* __restrict__ A, const u16* __restrict__ BT,
               const int* __restrict__ offsets, const int* __restrict__ ntiles,
               const int* __restrict__ map, const int* __restrict__ order,
               const float* __restrict__ bias,
               u16* __restrict__ Hout, float* __restrict__ Yout,
               u16* As, u16* Bs, int* ord) {
  constexpr int NCB = NB/128;
  const int xcd   = id & 7;
  const int sub   = id >> 3;
  const int ncolb = sub % NCB;
  const int slot  = xcd*SLOT_CHUNK + sub / NCB;
  if (slot >= ntiles[0]) return;             // uniform per block
  const int packed = map[slot];
  const int c      = packed >> 16;
  const int bstart = offsets[c];
  const int bend   = offsets[c+1];
  const int tile0  = bstart + (packed & 0xffff)*128;
  const int ncol0  = ncolb*128;

  const int tid  = threadIdx.x;
  const int wave = tid >> 6;
  const int lane = tid & 63;
  const int srow = (wave<<5) + (lane>>3);                 // staging row (local)
  const int scol = ((lane & 7) ^ ((lane >> 3) & 7)) << 3; // swizzled source chunk

  if (STAGE == 2 && tid < 128) {
    int gr = tile0 + tid;
    ord[tid] = order[gr < bend ? gr : bstart];
  }

  size_t a_off[4], b_off[4];
  const size_t bbase = (size_t)c * NB * K;
  #pragma unroll
  for (int i = 0; i < 4; ++i) {
    int ar = tile0 + srow + (i<<3);
    if (ar >= bend) ar = bend - 1;            // clamp reads (stores guarded)
    int arow = (STAGE == 1) ? order[ar] : ar; // STAGE1: gather row via order
    a_off[i] = (size_t)arow * K + scol;
    b_off[i] = bbase + (size_t)(ncol0 + srow + (i<<3)) * K + scol;
  }

  const int wr   = (wave >> 1) << 6;
  const int wc   = (wave & 1) << 6;
  const int quad = lane >> 4;
  const int l16  = lane & 15;
  const int sw   = l16 & 7;                   // read-side swizzle key (= row&7)

  f32x4 acc[4][4] = {};                       // acc[ni][mi] (swapped layout)

  for (int k0 = 0; k0 < K; k0 += 64) {
    #pragma unroll
    for (int i = 0; i < 4; ++i)
      load_lds16(A + a_off[i] + k0, &As[((wave<<5) + (i<<3))<<6]);
    #pragma unroll
    for (int i = 0; i < 4; ++i)
      load_lds16(BT + b_off[i] + k0, &Bs[((wave<<5) + (i<<3))<<6]);
    __syncthreads();
    #pragma unroll
    for (int kk = 0; kk < 64; kk += 32) {
      const int kc = (kk >> 3) + quad;        // desired 16B chunk index
      const int sc = (kc ^ sw) << 3;          // swizzled LDS slot (elems)
      bf16x8 af[4], bfr[4];
      #pragma unroll
      for (int mi = 0; mi < 4; ++mi)
        af[mi] = *reinterpret_cast<const bf16x8*>(&As[((wr + (mi<<4) + l16)<<6) + sc]);
      #pragma unroll
      for (int ni = 0; ni < 4; ++ni)
        bfr[ni] = *reinterpret_cast<const bf16x8*>(&Bs[((wc + (ni<<4) + l16)<<6) + sc]);
      #pragma unroll
      for (int ni = 0; ni < 4; ++ni)
        #pragma unroll
        for (int mi = 0; mi < 4; ++mi)
          acc[ni][mi] = __builtin_amdgcn_mfma_f32_16x16x32_bf16(bfr[ni], af[mi], acc[ni][mi], 0, 0, 0);
    }
    __syncthreads();
  }

  // ---- epilogue (swapped C/D layout): M-row = wr+mi*16+l16 (per-lane),
  //      N-cols = wc+ni*16+quad*4+{0..3} (per reg quad, consecutive) ----
  f32x4 bias4[4];
  #pragma unroll
  for (int ni = 0; ni < 4; ++ni)
    bias4[ni] = *reinterpret_cast<const f32x4*>(
        &bias[(size_t)c*NB + ncol0 + wc + (ni<<4) + (quad<<2)]);

  #pragma unroll
  for (int mi = 0; mi < 4; ++mi) {
    const int row_l = wr + (mi<<4) + l16;
    const int grow  = tile0 + row_l;
    if (grow < bend) {
      #pragma unroll
      for (int ni = 0; ni < 4; ++ni) {
        const int col = ncol0 + wc + (ni<<4) + (quad<<2);
        float v0 = acc[ni][mi][0] + bias4[ni][0];
        float v1 = acc[ni][mi][1] + bias4[ni][1];
        float v2 = acc[ni][mi][2] + bias4[ni][2];
        float v3 = acc[ni][mi][3] + bias4[ni][3];
        if (STAGE == 1) {
          v0 = __builtin_amdgcn_rcpf(1.0f + __expf(-v0));
          v1 = __builtin_amdgcn_rcpf(1.0f + __expf(-v1));
          v2 = __builtin_amdgcn_rcpf(1.0f + __expf(-v2));
          v3 = __builtin_amdgcn_rcpf(1.0f + __expf(-v3));
          uint2 pk;
          pk.x = (unsigned)f2b(v0) | ((unsigned)f2b(v1) << 16);
          pk.y = (unsigned)f2b(v2) | ((unsigned)f2b(v3) << 16);
          *reinterpret_cast<uint2*>(&Hout[(size_t)grow*NB + col]) = pk;
        } else {
          float4 o; o.x = v0; o.y = v1; o.z = v2; o.w = v3;
          *reinterpret_cast<float4*>(&Yout[(size_t)ord[row_l]*NB + col]) = o;
        }
      }
    }
  }
}

// ---------------- D2: GEMM1, persistent 1024 blocks (exactly 4/CU, no straggler round) ----
// blocks 0..63 handle jobs {b, b+1024} (same XCD: 1024 % 8 == 0); 64..1023 one job.
__global__ __launch_bounds__(256, 4)
void k_gemm1(const u16* __restrict__ Apack, const u16* __restrict__ W1T,
             const int* __restrict__ offsets, const int* __restrict__ ntiles,
             const int* __restrict__ map, const int* __restrict__ order,
             const float* __restrict__ b1, u16* __restrict__ Hout) {
  __shared__ __attribute__((aligned(16))) u16 As[128*64];
  __shared__ __attribute__((aligned(16))) u16 Bs[128*64];
  __shared__ int ord[128];
  #pragma unroll
  for (int j = 0; j < 2; ++j) {
    const int id = blockIdx.x + (j << 10);
    if (id < G1_JOBS) {
      if (j) __syncthreads();                // protect LDS reuse across jobs
      gemm_tile<LATD, HID, 1>(id, Apack, W1T, offsets, ntiles, map, order, b1,
                              Hout, nullptr, As, Bs, ord);
    }
  }
}

// ---------------- D3: GEMM2 (544 jobs < 1024 slots: direct) ----------------
__global__ __launch_bounds__(256, 4)
void k_gemm2(const u16* __restrict__ Hws, const u16* __restrict__ W2T,
             const int* __restrict__ offsets, const int* __restrict__ ntiles,
             const int* __restrict__ map, const int* __restrict__ order,
             const float* __restrict__ b2, float* __restrict__ Yout) {
  __shared__ __attribute__((aligned(16))) u16 As[128*64];
  __shared__ __attribute__((aligned(16))) u16 Bs[128*64];
  __shared__ int ord[128];
  gemm_tile<HID, OUTD, 2>(blockIdx.x, Hws, W2T, offsets, ntiles, map, order, b2,
                          nullptr, Yout, As, Bs, ord);
}

// ---------------- fallback (ws too small): naive per-sample MLP ----------------
__global__ void k_naive(const float* __restrict__ eps, const int* __restrict__ idx,
                        const float* __restrict__ mu, const float* __restrict__ rho,
                        const float* __restrict__ W1, const float* __restrict__ b1,
                        const float* __restrict__ W2, const float* __restrict__ b2,
                        float* __restrict__ out) {
  __shared__ float lat[LATD];
  __shared__ float h[HID];
  int n = blockIdx.x, t = threadIdx.x;
  int c = idx[n];
  float r = rho[c];
  float sg = (r > 20.f) ? r : log1pf(expf(r));
  for (int d = t; d < LATD; d += 256) lat[d] = eps[(size_t)n*LATD+d]*sg + mu[(size_t)c*LATD+d];
  __syncthreads();
  for (int j = t; j < HID; j += 256) {
    float a = b1[(size_t)c*HID+j];
    const float* w = W1 + (size_t)c*LATD*HID + j;
    for (int d = 0; d < LATD; ++d) a += lat[d]*w[(size_t)d*HID];
    h[j] = 1.f/(1.f+expf(-a));
  }
  __syncthreads();
  for (int o = t; o < OUTD; o += 256) {
    float a = b2[(size_t)c*OUTD+o];
    const float* w = W2 + (size_t)c*HID*OUTD + o;
    for (int j = 0; j < HID; ++j) a += h[j]*w[(size_t)j*OUTD];
    out[(size_t)n*OUTD+o] = a;
  }
}

extern "C" void kernel_launch(void* const* d_in, const int* in_sizes, int n_in,
                              void* d_out, int out_size, void* d_ws, size_t ws_size,
                              hipStream_t stream) {
  const float* eps = (const float*)d_in[0];
  const int*   idx = (const int*)d_in[1];
  const float* mu  = (const float*)d_in[2];
  const float* rho = (const float*)d_in[3];
  const float* W1  = (const float*)d_in[4];
  const float* b1  = (const float*)d_in[5];
  const float* W2  = (const float*)d_in[6];
  const float* b2  = (const float*)d_in[7];
  float* out = (float*)d_out;

  if (ws_size < WS_NEEDED) {     // insurance only
    k_naive<<<NS, 256, 0, stream>>>(eps, idx, mu, rho, W1, b1, W2, b2, out);
    return;
  }

  char* ws = (char*)d_ws;
  int*   offsets = (int*)(ws + 0);
  int*   ntiles  = (int*)(ws + 96);
  int*   map     = (int*)(ws + 128);
  int*   order   = (int*)(ws + ORDER_OFF);
  u16*   Apack   = (u16*)(ws + APACK_OFF);
  u16*   W1T     = (u16*)(ws + W1T_OFF);
  u16*   W2T     = (u16*)(ws + W2T_OFF);
  u16*   Hws     = (u16*)(ws + H_OFF);

  // D1: bucket (8) + pack (1024) + W1T (1024) + W2T (1024), all 256-thr blocks
  k_prep<<<PREP_NB, 256, 0, stream>>>(
      idx, rho, eps, mu, W1, W2, offsets, ntiles, map, order, Apack, W1T, W2T);
  // D2: GEMM1 gather-A [Nc x 512] @ [512 x 1024] -> sigmoid -> H (bf16, bucket order)
  k_gemm1<<<1024, 256, 0, stream>>>(
      Apack, W1T, offsets, ntiles, map, order, b1, Hws);
  // D3: GEMM2 [Nc x 1024] @ [1024 x 512] -> +b2 -> fp32 scatter out
  k_gemm2<<<G2_JOBS, 256, 0, stream>>>(
      Hws, W2T, offsets, ntiles, map, order, b2, out);
}